// Round 7
// baseline (98.271 us; speedup 1.0000x reference)
//
#include <hip/hip_runtime.h>
#include <hip/hip_bf16.h>
#include <math.h>

typedef __attribute__((ext_vector_type(8))) short short8;
typedef __attribute__((ext_vector_type(4))) float f32x4;

#define T_TOK 2048
#define D_DIM 512
#define F_DIM 2048
#define E_NUM 8
#define MAXT1 40   // >= sum_e ceil(cnt_e/64) <= 32+7

__device__ __forceinline__ unsigned short f2bf(float f) {
  union { float f; unsigned u; } c; c.f = f;
  unsigned u = c.u;
  return (unsigned short)((u + 0x7fffu + ((u >> 16) & 1u)) >> 16);
}

__device__ __forceinline__ void gld16(const void* g, void* l) {
  __builtin_amdgcn_global_load_lds((const __attribute__((address_space(1))) int*)g,
                                   (__attribute__((address_space(3))) int*)l, 16, 0, 0);
}

// ---- routing: logits (32-way K-split) + top-2 + weight; also converts x->bf16 ----
__global__ __launch_bounds__(256) void k_route(const float* __restrict__ x,
                                               const float* __restrict__ Wg,
                                               int* __restrict__ jbuf,
                                               float* __restrict__ wbuf,
                                               unsigned short* __restrict__ xb) {
  int gid = blockIdx.x * 256 + threadIdx.x;
  int t = gid >> 5, seg = gid & 31;
  const float* xp = x + (size_t)t * D_DIM + seg * 16;
  unsigned short* xo = xb + (size_t)t * D_DIM + seg * 16;
  float acc[8];
#pragma unroll
  for (int e = 0; e < 8; ++e) acc[e] = 0.f;
#pragma unroll
  for (int i = 0; i < 4; ++i) {
    float4 v = *(const float4*)(xp + i * 4);
    ushort4 o;
    o.x = f2bf(v.x); o.y = f2bf(v.y); o.z = f2bf(v.z); o.w = f2bf(v.w);
    *(ushort4*)(xo + i * 4) = o;
    const float* xs = (const float*)&v;
#pragma unroll
    for (int q = 0; q < 4; ++q) {
      int d = seg * 16 + i * 4 + q;
      const float4* wr = (const float4*)(Wg + (size_t)d * 8);
      float4 w0 = wr[0], w1 = wr[1];
      acc[0] += xs[q] * w0.x; acc[1] += xs[q] * w0.y;
      acc[2] += xs[q] * w0.z; acc[3] += xs[q] * w0.w;
      acc[4] += xs[q] * w1.x; acc[5] += xs[q] * w1.y;
      acc[6] += xs[q] * w1.z; acc[7] += xs[q] * w1.w;
    }
  }
#pragma unroll
  for (int off = 1; off < 32; off <<= 1)
#pragma unroll
    for (int e = 0; e < 8; ++e) acc[e] += __shfl_xor(acc[e], off);
  if (seg == 0) {
    float l0 = -1e30f, l1 = -1e30f; int i0 = 0, i1 = 0;
#pragma unroll
    for (int e = 0; e < 8; ++e) {
      float l = acc[e];
      if (l > l0) { l1 = l0; i1 = i0; l0 = l; i0 = e; }
      else if (l > l1) { l1 = l; i1 = e; }
    }
    int j; float w;
    if (i0 > i1) { j = i0; w = 1.f / (1.f + expf(l1 - l0)); }
    else         { j = i1; w = 1.f / (1.f + expf(l0 - l1)); }
    jbuf[t] = j; wbuf[t] = w;
  }
}

// ---- bucket: counts, bases, compact token list, compact tile list (BM=64) ----
__global__ __launch_bounds__(256) void k_bucket(const int* __restrict__ jbuf,
                                                int* __restrict__ cntp,
                                                int* __restrict__ basep,
                                                int* __restrict__ list,
                                                int* __restrict__ tl1,
                                                int* __restrict__ ntl) {
  __shared__ int scnt[8], scur[8];
  int tid = threadIdx.x;
  if (tid < 8) scnt[tid] = 0;
  __syncthreads();
  for (int t = tid; t < T_TOK; t += 256) atomicAdd(&scnt[jbuf[t]], 1);
  __syncthreads();
  if (tid == 0) {
    int run = 0;
    for (int e = 0; e < 8; ++e) {
      cntp[e] = scnt[e]; basep[e] = run; scur[e] = run;
      run += scnt[e];
    }
    int n1 = 0, bb = 0;
    for (int e = 0; e < 8; ++e) {
      for (int m = 0; m < scnt[e]; m += 64) tl1[n1++] = (e << 16) | (bb + m);
      bb += scnt[e];
    }
    ntl[0] = n1;
  }
  __syncthreads();
  for (int t = tid; t < T_TOK; t += 256) {
    int j = jbuf[t];
    int p = atomicAdd(&scur[j], 1);
    list[p] = t;
  }
}

// ---- pass 1: B-panel f32->bf16->registers (before loop), m-loop with R5 control flow ----
__global__ __launch_bounds__(256, 2) void k_ffn1(const unsigned short* __restrict__ xb,
                                                 const float* __restrict__ W1,
                                                 const float* __restrict__ W3,
                                                 const int* __restrict__ cntp,
                                                 const int* __restrict__ basep,
                                                 const int* __restrict__ list,
                                                 unsigned short* __restrict__ hbuf) {
  int e = blockIdx.x & 7, np = blockIdx.x >> 3;   // np: 64 panels of 32 f-cols
  int cnt = cntp[e];
  if (cnt == 0) return;
  int base = basep[e];
  int nm = (cnt + 63) >> 6;
  __shared__ unsigned short sA[64 * 512];   // 64 KB, XOR-swizzled 16B slots
  int tid = threadIdx.x, wv = tid >> 6, l = tid & 63;
  int wr = wv >> 1, wc = wv & 1;

  // B fragments for this wave's 16-col block, all K=512: f32 direct + cvt, once
  const float* b1p = W1 + (size_t)e * D_DIM * F_DIM + np * 32 + wc * 16 + (l & 15);
  const float* b3p = W3 + (size_t)e * D_DIM * F_DIM + np * 32 + wc * 16 + (l & 15);
  int krow = (l >> 4) * 8;
  short8 B1[16], B3[16];
#pragma unroll
  for (int kf = 0; kf < 16; ++kf) {
    short8 o1, o3;
#pragma unroll
    for (int j = 0; j < 8; ++j) {
      o1[j] = (short)f2bf(b1p[(size_t)(kf * 32 + krow + j) * F_DIM]);
      o3[j] = (short)f2bf(b3p[(size_t)(kf * 32 + krow + j) * F_DIM]);
    }
    B1[kf] = o1; B3[kf] = o3;
  }

  for (int im = 0; im < nm; ++im) {
    int g0 = base + im * 64;
    int lim = base + cnt;
    // stage A tile [64][512] (wave wv: rows wv*16..+15), swizzled source slots
#pragma unroll
    for (int it = 0; it < 16; ++it) {
      int row = wv * 16 + it;
      int gr = g0 + row; if (gr >= lim) gr = lim - 1;
      int tok = list[gr];
      int slot = (l & 56) | ((l & 7) ^ (row & 7));
      gld16(xb + (size_t)tok * D_DIM + slot * 8, sA + row * 512);
    }
    __syncthreads();   // drain gld16, publish sA

    f32x4 au[2], av[2];
#pragma unroll
    for (int i = 0; i < 2; ++i) {
      au[i] = (f32x4){0.f, 0.f, 0.f, 0.f};
      av[i] = (f32x4){0.f, 0.f, 0.f, 0.f};
    }
#pragma unroll
    for (int kf = 0; kf < 16; ++kf) {
      short8 a[2];
#pragma unroll
      for (int i = 0; i < 2; ++i) {
        int r = wr * 32 + i * 16 + (l & 15);
        int slot = kf * 4 + (l >> 4);
        int swz = (slot & 56) | ((slot & 7) ^ (r & 7));
        a[i] = *(const short8*)(sA + r * 512 + swz * 8);
      }
#pragma unroll
      for (int i = 0; i < 2; ++i) {
        au[i] = __builtin_amdgcn_mfma_f32_16x16x32_bf16(a[i], B1[kf], au[i], 0, 0, 0);
        av[i] = __builtin_amdgcn_mfma_f32_16x16x32_bf16(a[i], B3[kf], av[i], 0, 0, 0);
      }
    }
    __syncthreads();   // all LDS reads done before next m-iter restages

    int cloc = l & 15, rb = (l >> 4) * 4;
    int col = np * 32 + wc * 16 + cloc;
#pragma unroll
    for (int i = 0; i < 2; ++i)
#pragma unroll
      for (int r = 0; r < 4; ++r) {
        int gr = g0 + wr * 32 + i * 16 + rb + r;
        if (gr < lim) {
          float uu = au[i][r], vv = av[i][r];
          float hh = (uu / (1.f + expf(-uu))) * vv;
          hbuf[(size_t)gr * F_DIM + col] = f2bf(hh);
        }
      }
  }
}

// ---- pass 2: y = h @ W2, out[tok]=w*y; BM=64 BN=32 BK=128, A dbuf + B ping-pong ----
__global__ __launch_bounds__(256, 3) void k_ffn2(const unsigned short* __restrict__ hbuf,
                                                 const float* __restrict__ W2,
                                                 const int* __restrict__ cntp,
                                                 const int* __restrict__ basep,
                                                 const int* __restrict__ list,
                                                 const int* __restrict__ tl1,
                                                 const int* __restrict__ ntl,
                                                 const float* __restrict__ wbuf,
                                                 float* __restrict__ out) {
  if ((int)blockIdx.x >= ntl[0]) return;
  int pk = tl1[blockIdx.x];
  int e = pk >> 16, g0 = pk & 0xffff;
  int lim = basep[e] + cntp[e];
  int nt = blockIdx.y;               // 16 panels of 32 d-cols
  __shared__ unsigned short sA[2 * 8192];   // 2 x 16 KB chunks [64][128], swizzled
  int tid = threadIdx.x, wv = tid >> 6, l = tid & 63;
  int wr = wv >> 1, wc = wv & 1;

  auto stage = [&](int buf, int ck) {
#pragma unroll
    for (int it = 0; it < 4; ++it) {
      int row0 = it * 16 + wv * 4;             // wave-uniform
      int row = row0 + (l >> 4);
      int gr = g0 + row; if (gr > T_TOK - 1) gr = T_TOK - 1;
      int sl = (l & 8) | ((l & 7) ^ (row & 7));
      gld16(hbuf + (size_t)gr * F_DIM + ck * 128 + sl * 8, sA + buf * 8192 + row0 * 128);
    }
  };

  const float* b2p = W2 + (size_t)e * F_DIM * D_DIM + nt * 32 + wc * 16 + (l & 15);
  int krow = (l >> 4) * 8;

  short8 Ba[4], Bb[4];
  auto loadB = [&](short8* B, int ck) {
#pragma unroll
    for (int kf = 0; kf < 4; ++kf) {
      short8 o;
#pragma unroll
      for (int j = 0; j < 8; ++j)
        o[j] = (short)f2bf(b2p[(size_t)(ck * 128 + kf * 32 + krow + j) * D_DIM]);
      B[kf] = o;
    }
  };

  f32x4 acc[2];
  acc[0] = (f32x4){0.f, 0.f, 0.f, 0.f};
  acc[1] = (f32x4){0.f, 0.f, 0.f, 0.f};

  auto compute = [&](const short8* B, int cur) {
#pragma unroll
    for (int kf = 0; kf < 4; ++kf) {
      short8 a[2];
#pragma unroll
      for (int i = 0; i < 2; ++i) {
        int r = wr * 32 + i * 16 + (l & 15);
        int slot = kf * 4 + (l >> 4);
        int swz = (slot & 8) | ((slot & 7) ^ (r & 7));
        a[i] = *(const short8*)(sA + cur * 8192 + r * 128 + swz * 8);
      }
      acc[0] = __builtin_amdgcn_mfma_f32_16x16x32_bf16(a[0], B[kf], acc[0], 0, 0, 0);
      acc[1] = __builtin_amdgcn_mfma_f32_16x16x32_bf16(a[1], B[kf], acc[1], 0, 0, 0);
    }
  };

  stage(0, 0);
  loadB(Ba, 0);
  __syncthreads();
  int cur = 0;
  for (int ck = 0; ck < 16; ck += 2) {
    stage(cur ^ 1, ck + 1);
    loadB(Bb, ck + 1);
    compute(Ba, cur);
    __syncthreads();
    cur ^= 1;
    if (ck + 2 < 16) {
      stage(cur ^ 1, ck + 2);
      loadB(Ba, ck + 2);
    }
    compute(Bb, cur);
    __syncthreads();
    cur ^= 1;
  }

  int cloc = l & 15, rb = (l >> 4) * 4;
#pragma unroll
  for (int i = 0; i < 2; ++i)
#pragma unroll
    for (int r = 0; r < 4; ++r) {
      int gr = g0 + wr * 32 + i * 16 + rb + r;
      if (gr < lim) {
        int tok = list[gr];
        out[(size_t)tok * D_DIM + nt * 32 + wc * 16 + cloc] = wbuf[tok] * acc[i][r];
      }
    }
}

// ---------------- launch ----------------
extern "C" void kernel_launch(void* const* d_in, const int* in_sizes, int n_in,
                              void* d_out, int out_size, void* d_ws, size_t ws_size,
                              hipStream_t stream) {
  const float* x  = (const float*)d_in[0];
  const float* Wg = (const float*)d_in[1];
  const float* W1 = (const float*)d_in[2];
  const float* W2 = (const float*)d_in[3];
  const float* W3 = (const float*)d_in[4];
  float* out = (float*)d_out;
  char* ws = (char*)d_ws;

  int*            jbuf  = (int*)(ws + 0);
  float*          wbuf  = (float*)(ws + 8192);
  int*            cntp  = (int*)(ws + 16384);
  int*            basep = (int*)(ws + 16448);
  int*            list  = (int*)(ws + 16640);      // int[2048]
  int*            tl1   = (int*)(ws + 24832);      // int[40]
  int*            ntl   = (int*)(ws + 25600);      // int[2]
  unsigned short* xb    = (unsigned short*)(ws + 32768);             // bf16 [2048][512]
  unsigned short* hbuf  = (unsigned short*)(ws + 32768 + 2097152);   // bf16 [2048][2048]

  k_route<<<dim3(256), dim3(256), 0, stream>>>(x, Wg, jbuf, wbuf, xb);
  k_bucket<<<dim3(1), dim3(256), 0, stream>>>(jbuf, cntp, basep, list, tl1, ntl);
  k_ffn1<<<dim3(512), dim3(256), 0, stream>>>(xb, W1, W3, cntp, basep, list, hbuf);
  k_ffn2<<<dim3(MAXT1, 16), dim3(256), 0, stream>>>(hbuf, W2, cntp, basep, list, tl1, ntl, wbuf, out);
}